// Round 3
// baseline (540.560 us; speedup 1.0000x reference)
//
#include <hip/hip_runtime.h>
#include <hip/hip_bf16.h>

// LlamaAttention_49392123904401 — per-token head-mixing "attention":
//   q,k,v = x@W{q,k,v}^T ; per token: scores[h][t] = q_h.k_t/8, softmax over t,
//   z = P@v ; out = z@Wo^T.  Device dtype (fp32 vs bf16) detected at runtime;
//   compute in bf16 MFMA with fp32 accum; output written in detected dtype.

typedef short bf16x8 __attribute__((ext_vector_type(8)));   // 8 bf16 = 4 VGPRs
typedef float f32x4  __attribute__((ext_vector_type(4)));

__device__ __forceinline__ float bf2f(short u) {
    union { unsigned int ui; float f; } cv;
    cv.ui = ((unsigned int)(unsigned short)u) << 16;
    return cv.f;
}
__device__ __forceinline__ short f2bf(float f) {
    __hip_bfloat16 h = __float2bfloat16(f);
    return *reinterpret_cast<short*>(&h);
}

// async global->LDS, 16B per lane. LDS dest = wave-uniform base + lane*16.
__device__ __forceinline__ void gload_lds16(const void* g, void* lds) {
    const unsigned __attribute__((address_space(1)))* gp =
        reinterpret_cast<const unsigned __attribute__((address_space(1)))*>((unsigned long long)g);
    unsigned __attribute__((address_space(3)))* lp =
        reinterpret_cast<unsigned __attribute__((address_space(3)))*>(
            (unsigned int)(unsigned long long)lds);
    __builtin_amdgcn_global_load_lds(gp, lp, 16, 0, 0);
}

// ---------------------------------------------------------------------------
// dtype sniffer on X. u32 bits 14:7: bf16 pairs -> exponent of the LOW element
// (~100% in [0x70,0x87] for N(0,1)); fp32 -> mantissa bits (~9.4% in range).
// flag: 1 = fp32 inputs, 0 = bf16 inputs.
// ---------------------------------------------------------------------------
__global__ void detect_dtype(const unsigned* __restrict__ x, int* __restrict__ flag) {
    __shared__ int cnt;
    if (threadIdx.x == 0) cnt = 0;
    __syncthreads();
    int c = 0;
    for (int i = threadIdx.x; i < 4096; i += 256) {
        const unsigned u = x[(long)i * 4001 + 3];       // max idx 16.39M < 16.77M
        const unsigned b = (u >> 7) & 0xFF;
        c += (b >= 0x70 && b <= 0x87) ? 1 : 0;
    }
    atomicAdd(&cnt, c);
    __syncthreads();
    if (threadIdx.x == 0) *flag = (cnt > 2048) ? 0 : 1;   // HIGH => bf16
}

// convert n elements (n % 8 == 0) at element offset eoff to bf16.
__global__ void convert_any(const void* __restrict__ src, long eoff,
                            short* __restrict__ dst, long n,
                            const int* __restrict__ flag) {
    const int f = *flag;                                 // uniform branch
    const long step = (long)gridDim.x * blockDim.x * 8;
    for (long i = ((long)blockIdx.x * blockDim.x + threadIdx.x) * 8; i < n; i += step) {
        if (f) {
            const float* s = (const float*)src + eoff + i;
            const f32x4 a = *(const f32x4*)s;
            const f32x4 b = *(const f32x4*)(s + 4);
            bf16x8 o;
            o[0] = f2bf(a[0]); o[1] = f2bf(a[1]); o[2] = f2bf(a[2]); o[3] = f2bf(a[3]);
            o[4] = f2bf(b[0]); o[5] = f2bf(b[1]); o[6] = f2bf(b[2]); o[7] = f2bf(b[3]);
            *(bf16x8*)(dst + i) = o;
        } else {
            *(bf16x8*)(dst + i) = *(const bf16x8*)((const short*)src + eoff + i);
        }
    }
}

// ---------------------------------------------------------------------------
// C[M,N] = A[M,K] @ W[N,K]^T, bf16 in, fp32 accum. K=N=1024 fixed.
// BM=BN=128, BK=32; 256 threads = 4 waves (2x2), each wave 64x64 output.
// Epilogue dtype: flag_fp32 ? (*flag_fp32 ? fp32 : bf16) : bf16.
// ---------------------------------------------------------------------------
__device__ __forceinline__ void gemm_bt_core(const short* __restrict__ A,
                                             const short* __restrict__ W,
                                             void* __restrict__ C,
                                             const int* flag_fp32,
                                             short* As, short* Bs,
                                             long m0, int n0) {
    constexpr int K = 1024, N = 1024, BK = 32;
    const int tid  = threadIdx.x;
    const int lane = tid & 63;
    const int w    = tid >> 6;
    const int wm = w >> 1, wn = w & 1;
    const int f = flag_fp32 ? *flag_fp32 : 0;

    f32x4 acc[4][4] = {};

    const int srow = lane >> 2;        // row within a 16-row staging segment
    const int scol = (lane & 3) * 8;   // bf16 column within BK

    for (int k0 = 0; k0 < K; k0 += BK) {
        __syncthreads();               // previous compute done before overwrite
        #pragma unroll
        for (int i = 0; i < 2; ++i) {
            const int seg = w * 2 + i;                                 // 0..7
            gload_lds16(A + (m0 + seg * 16 + srow) * K + k0 + scol, As + seg * 512);
            gload_lds16(W + (long)(n0 + seg * 16 + srow) * K + k0 + scol, Bs + seg * 512);
        }
        __syncthreads();               // vmcnt(0) drain: staging visible

        bf16x8 af[4], bfr[4];
        #pragma unroll
        for (int mf = 0; mf < 4; ++mf)
            af[mf] = *(const bf16x8*)(As + (wm * 64 + mf * 16 + (lane & 15)) * BK + (lane >> 4) * 8);
        #pragma unroll
        for (int nf = 0; nf < 4; ++nf)
            bfr[nf] = *(const bf16x8*)(Bs + (wn * 64 + nf * 16 + (lane & 15)) * BK + (lane >> 4) * 8);
        #pragma unroll
        for (int mf = 0; mf < 4; ++mf)
            #pragma unroll
            for (int nf = 0; nf < 4; ++nf)
                acc[mf][nf] = __builtin_amdgcn_mfma_f32_16x16x32_bf16(
                                  af[mf], bfr[nf], acc[mf][nf], 0, 0, 0);
    }

    // C/D layout (m89): col = lane&15, row = (lane>>4)*4 + r
    #pragma unroll
    for (int mf = 0; mf < 4; ++mf) {
        #pragma unroll
        for (int nf = 0; nf < 4; ++nf) {
            const int  col   = n0 + wn * 64 + nf * 16 + (lane & 15);
            const long rbase = m0 + wm * 64 + mf * 16 + (lane >> 4) * 4;
            if (f) {
                float* Cf = (float*)C;
                #pragma unroll
                for (int r = 0; r < 4; ++r)
                    Cf[(rbase + r) * N + col] = acc[mf][nf][r];
            } else {
                short* Cs = (short*)C;
                #pragma unroll
                for (int r = 0; r < 4; ++r)
                    Cs[(rbase + r) * N + col] = f2bf(acc[mf][nf][r]);
            }
        }
    }
}

__global__ __launch_bounds__(256) void gemm_bt_out(const short* __restrict__ A,
                                                   const short* __restrict__ W,
                                                   void* __restrict__ C,
                                                   long moff,
                                                   const int* __restrict__ flag) {
    __shared__ short As[128 * 32];
    __shared__ short Bs[128 * 32];
    // C is the FULL output base; row offset moff selects the chunk.
    gemm_bt_core(A - moff * 1024, W, C, flag, As, Bs,
                 moff + (long)blockIdx.x * 128, blockIdx.y * 128);
}

// QKV fused over grid.z (0=Q,1=K,2=V); always bf16 out (internal buffers)
__global__ __launch_bounds__(256) void gemm_qkv(const short* __restrict__ A,
                                                const short* __restrict__ W0,
                                                const short* __restrict__ W1,
                                                const short* __restrict__ W2,
                                                short* __restrict__ C0,
                                                short* __restrict__ C1,
                                                short* __restrict__ C2) {
    __shared__ short As[128 * 32];
    __shared__ short Bs[128 * 32];
    const short* W = (blockIdx.z == 0) ? W0 : (blockIdx.z == 1) ? W1 : W2;
    short*       C = (blockIdx.z == 0) ? C0 : (blockIdx.z == 1) ? C1 : C2;
    gemm_bt_core(A, W, C, nullptr, As, Bs, (long)blockIdx.x * 128, blockIdx.y * 128);
}

// ---------------------------------------------------------------------------
// Per-token head mixing: scores = Q[16,64] @ K[16,64]^T / 8, softmax rows,
// Z = P @ V[16,64].  One wave per token, 4 tokens per 256-thread block.
// ---------------------------------------------------------------------------
__global__ __launch_bounds__(256) void attn_mix(const short* __restrict__ Q,
                                                const short* __restrict__ K,
                                                const short* __restrict__ V,
                                                short* __restrict__ Z) {
    constexpr int RS = 72;
    __shared__ short sq[4][16 * RS];
    __shared__ short sk[4][16 * RS];
    __shared__ short sv[4][16 * RS];
    __shared__ float sp[4][256];

    const int  tid  = threadIdx.x;
    const int  lane = tid & 63;
    const int  w    = tid >> 6;
    const long tok  = (long)blockIdx.x * 4 + w;

    const short* qg = Q + tok * 1024;
    const short* kg = K + tok * 1024;
    const short* vg = V + tok * 1024;

    #pragma unroll
    for (int it = 0; it < 2; ++it) {
        const int c   = lane + 64 * it;       // 16B chunk id, 0..127
        const int row = c >> 3;
        const int cc  = (c & 7) * 8;
        *(bf16x8*)&sq[w][row * RS + cc] = *(const bf16x8*)(qg + c * 8);
        *(bf16x8*)&sk[w][row * RS + cc] = *(const bf16x8*)(kg + c * 8);
        *(bf16x8*)&sv[w][row * RS + cc] = *(const bf16x8*)(vg + c * 8);
    }
    __syncthreads();

    const int h  = lane >> 2;                 // head (score row)
    const int t0 = (lane & 3) * 4;            // 4 keys per lane
    float sc[4] = {0.f, 0.f, 0.f, 0.f};
    for (int d = 0; d < 64; ++d) {
        const float qv = bf2f(sq[w][h * RS + d]);
        #pragma unroll
        for (int j = 0; j < 4; ++j)
            sc[j] += qv * bf2f(sk[w][(t0 + j) * RS + d]);
    }
    #pragma unroll
    for (int j = 0; j < 4; ++j) sc[j] *= 0.125f;   // 1/sqrt(64)

    float mx = fmaxf(fmaxf(sc[0], sc[1]), fmaxf(sc[2], sc[3]));
    mx = fmaxf(mx, __shfl_xor(mx, 1));
    mx = fmaxf(mx, __shfl_xor(mx, 2));
    float ex[4], s = 0.f;
    #pragma unroll
    for (int j = 0; j < 4; ++j) { ex[j] = __expf(sc[j] - mx); s += ex[j]; }
    s += __shfl_xor(s, 1);
    s += __shfl_xor(s, 2);
    const float inv = 1.f / s;
    #pragma unroll
    for (int j = 0; j < 4; ++j) sp[w][h * 16 + t0 + j] = ex[j] * inv;
    __syncthreads();

    const int dbase = (lane & 3) * 16;
    float o[16] = {};
    for (int t = 0; t < 16; ++t) {
        const float p = sp[w][h * 16 + t];
        const bf16x8 v0 = *(const bf16x8*)&sv[w][t * RS + dbase];
        const bf16x8 v1 = *(const bf16x8*)&sv[w][t * RS + dbase + 8];
        #pragma unroll
        for (int e = 0; e < 8; ++e) {
            o[e]     += p * bf2f(v0[e]);
            o[e + 8] += p * bf2f(v1[e]);
        }
    }
    bf16x8 ov0, ov1;
    #pragma unroll
    for (int e = 0; e < 8; ++e) { ov0[e] = f2bf(o[e]); ov1[e] = f2bf(o[e + 8]); }
    *(bf16x8*)(Z + tok * 1024 + lane * 16)     = ov0;
    *(bf16x8*)(Z + tok * 1024 + lane * 16 + 8) = ov1;
}

// ---------------------------------------------------------------------------
extern "C" void kernel_launch(void* const* d_in, const int* in_sizes, int n_in,
                              void* d_out, int out_size, void* d_ws, size_t ws_size,
                              hipStream_t stream) {
    const void* X = d_in[0];                   // [32768,1024] fp32 (or bf16)

    const long TOT = 32768;
    constexpr long WELEM = 1024 * 1024;

    char* ws   = (char*)d_ws;
    int*  flag = (int*)ws;                     // 256 B reserved
    short* Wqb = (short*)(ws + 256);
    short* Wkb = Wqb + WELEM;
    short* Wvb = Wkb + WELEM;
    short* Wob = Wvb + WELEM;
    short* dyn = Wob + WELEM;

    const size_t fixed = 256 + 4 * WELEM * 2;  // flag + weights ≈ 8.4 MB
    long chunk = 128;
    const long tiers[4] = {32768, 8192, 2048, 512};
    for (int i = 0; i < 4; ++i)
        if (fixed + (size_t)6 * tiers[i] * 1024 * 2 <= ws_size) { chunk = tiers[i]; break; }

    short* Xb = dyn;                 // chunk*1024 bf16
    short* Qb = Xb + chunk * 1024;
    short* Kb = Qb + chunk * 1024;
    short* Vb = Kb + chunk * 1024;
    short* Zb = Vb + chunk * 1024;   // chunk*1024 bf16

    detect_dtype<<<1, 256, 0, stream>>>((const unsigned*)X, flag);
    convert_any<<<512, 256, 0, stream>>>(d_in[1], 0, Wqb, WELEM, flag);
    convert_any<<<512, 256, 0, stream>>>(d_in[2], 0, Wkb, WELEM, flag);
    convert_any<<<512, 256, 0, stream>>>(d_in[3], 0, Wvb, WELEM, flag);
    convert_any<<<512, 256, 0, stream>>>(d_in[4], 0, Wob, WELEM, flag);

    for (long t0 = 0; t0 < TOT; t0 += chunk) {
        convert_any<<<2048, 256, 0, stream>>>(X, t0 * 1024, Xb, chunk * 1024, flag);
        gemm_qkv<<<dim3(chunk / 128, 8, 3), 256, 0, stream>>>(Xb, Wqb, Wkb, Wvb, Qb, Kb, Vb);
        attn_mix<<<dim3(chunk / 4), 256, 0, stream>>>(Qb, Kb, Vb, Zb);
        // Zb holds rows [0,chunk); output rows [t0, t0+chunk). A is rebased
        // inside gemm_bt_out so C indexing uses absolute row t0+...
        gemm_bt_out<<<dim3(chunk / 128, 8), 256, 0, stream>>>(Zb, Wob, d_out, t0, flag);
    }
}

// Round 4
// 429.745 us; speedup vs baseline: 1.2579x; 1.2579x over previous
//
#include <hip/hip_runtime.h>
#include <hip/hip_bf16.h>

// LlamaAttention_49392123904401 — per-token head-mixing "attention".
// fp32 inputs (runtime-detected), bf16 MFMA compute, output in input dtype.
// This round: 256^2/BK=64 8-wave GEMM with LDS XOR-swizzle (T2, both-sides),
// counted vmcnt across raw barriers (T4), setprio (T5), XCD A-panel grouping (T1).

typedef short bf16x8 __attribute__((ext_vector_type(8)));   // 8 bf16 = 4 VGPRs
typedef float f32x4  __attribute__((ext_vector_type(4)));

__device__ __forceinline__ float bf2f(short u) {
    union { unsigned int ui; float f; } cv;
    cv.ui = ((unsigned int)(unsigned short)u) << 16;
    return cv.f;
}
__device__ __forceinline__ short f2bf(float f) {
    __hip_bfloat16 h = __float2bfloat16(f);
    return *reinterpret_cast<short*>(&h);
}

// async global->LDS, 16B per lane. LDS dest = wave-uniform base + lane*16.
__device__ __forceinline__ void gload_lds16(const void* g, void* lds) {
    const unsigned __attribute__((address_space(1)))* gp =
        reinterpret_cast<const unsigned __attribute__((address_space(1)))*>((unsigned long long)g);
    unsigned __attribute__((address_space(3)))* lp =
        reinterpret_cast<unsigned __attribute__((address_space(3)))*>(
            (unsigned int)(unsigned long long)lds);
    __builtin_amdgcn_global_load_lds(gp, lp, 16, 0, 0);
}

// ---------------------------------------------------------------------------
// dtype sniffer (flag: 1 = fp32 inputs, 0 = bf16 inputs).
// ---------------------------------------------------------------------------
__global__ void detect_dtype(const unsigned* __restrict__ x, int* __restrict__ flag) {
    __shared__ int cnt;
    if (threadIdx.x == 0) cnt = 0;
    __syncthreads();
    int c = 0;
    for (int i = threadIdx.x; i < 4096; i += 256) {
        const unsigned u = x[(long)i * 4001 + 3];
        const unsigned b = (u >> 7) & 0xFF;
        c += (b >= 0x70 && b <= 0x87) ? 1 : 0;
    }
    atomicAdd(&cnt, c);
    __syncthreads();
    if (threadIdx.x == 0) *flag = (cnt > 2048) ? 0 : 1;   // HIGH => bf16
}

// convert n elements (n % 8 == 0) at element offset eoff to bf16.
__global__ void convert_any(const void* __restrict__ src, long eoff,
                            short* __restrict__ dst, long n,
                            const int* __restrict__ flag) {
    const int f = *flag;
    const long step = (long)gridDim.x * blockDim.x * 8;
    for (long i = ((long)blockIdx.x * blockDim.x + threadIdx.x) * 8; i < n; i += step) {
        if (f) {
            const float* s = (const float*)src + eoff + i;
            const f32x4 a = *(const f32x4*)s;
            const f32x4 b = *(const f32x4*)(s + 4);
            bf16x8 o;
            o[0] = f2bf(a[0]); o[1] = f2bf(a[1]); o[2] = f2bf(a[2]); o[3] = f2bf(a[3]);
            o[4] = f2bf(b[0]); o[5] = f2bf(b[1]); o[6] = f2bf(b[2]); o[7] = f2bf(b[3]);
            *(bf16x8*)(dst + i) = o;
        } else {
            *(bf16x8*)(dst + i) = *(const bf16x8*)((const short*)src + eoff + i);
        }
    }
}

// ---------------------------------------------------------------------------
// 256x256 tile GEMM core: C[m0..m0+255][n0..n0+255] = A[.][1024] @ W[.][1024]^T
// 512 threads = 8 waves (2 M x 4 N), per-wave 128x64 output (8x4 frags).
// BK=64, 16 K-tiles, 2-deep LDS double-buffer, counted vmcnt(8), raw barriers.
// LDS k-chunk XOR swizzle: phys_kc = kc ^ (row&7)  (16B chunks, 8 per row).
// Staging pre-applies the inverse swizzle on the GLOBAL source address.
// ---------------------------------------------------------------------------
__device__ __forceinline__ void gemm256_core(const short* __restrict__ A,
                                             const short* __restrict__ W,
                                             void* __restrict__ C,
                                             const int* flag_fp32,
                                             long m0, int n0, short* lds) {
    constexpr int K = 1024, N = 1024;
    const int tid  = threadIdx.x;
    const int lane = tid & 63;
    const int wid  = tid >> 6;
    const int wm = wid >> 2, wn = wid & 3;

    short* A0 = lds;              // 16384 shorts = 32KB
    short* B0 = lds + 16384;
    short* A1 = lds + 32768;
    short* B1 = lds + 49152;

    // staging source offsets: thread covers (row = i*64 + tid>>3, phys kc = tid&7)
    // logical kc = phys ^ (row&7); global elem = row*K + kc*8
    const int srl = tid >> 3;                    // 0..63
    const int kcs = (tid & 7) ^ (srl & 7);       // logical k-chunk for this lane
    int aoff[4], boff[4];
    #pragma unroll
    for (int i = 0; i < 4; ++i) {
        const int row = i * 64 + srl;
        aoff[i] = (int)((m0 + row) * K + kcs * 8);
        boff[i] = (n0 + row) * K + kcs * 8;
    }
    const int ldsw = wid * 512;                  // wave's lane0 slot (shorts)

    auto STAGE = [&](short* bA, short* bB, int t) {
        const int kadd = t * 64;
        #pragma unroll
        for (int i = 0; i < 4; ++i)
            gload_lds16(A + aoff[i] + kadd, bA + i * 4096 + ldsw);
        #pragma unroll
        for (int i = 0; i < 4; ++i)
            gload_lds16(W + boff[i] + kadd, bB + i * 4096 + ldsw);
    };

    f32x4 acc[8][4] = {};

    auto COMPUTE = [&](const short* bA, const short* bB) {
        #pragma unroll
        for (int ks = 0; ks < 2; ++ks) {
            const int kx8 = (((ks * 4 + (lane >> 4)) ^ (lane & 7))) * 8;
            bf16x8 af[8], bfr[4];
            #pragma unroll
            for (int mf = 0; mf < 8; ++mf)
                af[mf] = *(const bf16x8*)(bA + (wm * 128 + mf * 16 + (lane & 15)) * 64 + kx8);
            #pragma unroll
            for (int nf = 0; nf < 4; ++nf)
                bfr[nf] = *(const bf16x8*)(bB + (wn * 64 + nf * 16 + (lane & 15)) * 64 + kx8);
            __builtin_amdgcn_s_setprio(1);
            #pragma unroll
            for (int mf = 0; mf < 8; ++mf)
                #pragma unroll
                for (int nf = 0; nf < 4; ++nf)
                    acc[mf][nf] = __builtin_amdgcn_mfma_f32_16x16x32_bf16(
                                      af[mf], bfr[nf], acc[mf][nf], 0, 0, 0);
            __builtin_amdgcn_s_setprio(0);
        }
    };

    // prologue: 2 tiles in flight (16 loads/wave outstanding)
    STAGE(A0, B0, 0);
    STAGE(A1, B1, 1);

    // steady state: compute t, then stage t+2 into the buffer just freed.
    for (int tt = 0; tt < 7; ++tt) {
        const int t = tt * 2;
        asm volatile("s_waitcnt vmcnt(8)" ::: "memory");   // tile t landed
        __builtin_amdgcn_s_barrier();
        asm volatile("" ::: "memory");
        COMPUTE(A0, B0);
        asm volatile("" ::: "memory");
        __builtin_amdgcn_s_barrier();                      // all reads of buf0 done
        STAGE(A0, B0, t + 2);
        asm volatile("s_waitcnt vmcnt(8)" ::: "memory");   // tile t+1 landed
        __builtin_amdgcn_s_barrier();
        asm volatile("" ::: "memory");
        COMPUTE(A1, B1);
        asm volatile("" ::: "memory");
        __builtin_amdgcn_s_barrier();
        STAGE(A1, B1, t + 3);
    }
    // t=14 (buf0): tiles 14,15 outstanding
    asm volatile("s_waitcnt vmcnt(8)" ::: "memory");
    __builtin_amdgcn_s_barrier();
    asm volatile("" ::: "memory");
    COMPUTE(A0, B0);
    // t=15 (buf1): only tile 15 outstanding
    asm volatile("s_waitcnt vmcnt(0)" ::: "memory");
    __builtin_amdgcn_s_barrier();
    asm volatile("" ::: "memory");
    COMPUTE(A1, B1);

    // epilogue: C/D layout col=lane&15, row=(lane>>4)*4+r
    const int f = flag_fp32 ? *flag_fp32 : 0;
    #pragma unroll
    for (int mf = 0; mf < 8; ++mf) {
        #pragma unroll
        for (int nf = 0; nf < 4; ++nf) {
            const int  col   = n0 + wn * 64 + nf * 16 + (lane & 15);
            const long rbase = m0 + wm * 128 + mf * 16 + (lane >> 4) * 4;
            if (f) {
                float* Cf = (float*)C;
                #pragma unroll
                for (int r = 0; r < 4; ++r)
                    Cf[(rbase + r) * N + col] = acc[mf][nf][r];
            } else {
                short* Cs = (short*)C;
                #pragma unroll
                for (int r = 0; r < 4; ++r)
                    Cs[(rbase + r) * N + col] = f2bf(acc[mf][nf][r]);
            }
        }
    }
}

// QKV: 1-D grid, nwg = (Mc/256)*12, nwg % 8 == 0.
// XCD-bijective remap with (y,z) innermost so the 12 blocks sharing an
// A-panel run on one XCD (A-panel fetched ~once per XCD).
__global__ __launch_bounds__(512, 2) void gemm_qkv256(const short* __restrict__ A,
                                                      const short* __restrict__ W0,
                                                      const short* __restrict__ W1,
                                                      const short* __restrict__ W2,
                                                      short* __restrict__ C0,
                                                      short* __restrict__ C1,
                                                      short* __restrict__ C2) {
    __shared__ __align__(16) short lds[65536];            // 128 KiB
    const int nwg = gridDim.x;
    const int q8  = nwg >> 3;
    const int d   = blockIdx.x;
    const int lin = (d & 7) * q8 + (d >> 3);
    const int x   = lin / 12;
    const int r   = lin - x * 12;
    const int y   = r >> 2;          // 0..2? no: r in 0..11, y = r/3 below
    const int yy  = r / 3;           // 0..3  (n-tile)
    const int z   = r - yy * 3;      // 0..2  (Q/K/V)
    (void)y;
    const short* W = (z == 0) ? W0 : (z == 1) ? W1 : W2;
    short*       C = (z == 0) ? C0 : (z == 1) ? C1 : C2;
    gemm256_core(A, W, C, nullptr, (long)x * 256, yy * 256, lds);
}

// Output GEMM: 1-D grid, nwg = (Mc/256)*4. A pre-rebased by caller (A - moff*K).
__global__ __launch_bounds__(512, 2) void gemm_out256(const short* __restrict__ A,
                                                      const short* __restrict__ W,
                                                      void* __restrict__ C,
                                                      long moff,
                                                      const int* __restrict__ flag) {
    __shared__ __align__(16) short lds[65536];
    const int nwg = gridDim.x;
    const int q8  = nwg >> 3;
    const int d   = blockIdx.x;
    const int lin = (d & 7) * q8 + (d >> 3);
    const int x   = lin >> 2;
    const int yy  = lin & 3;
    gemm256_core(A, W, C, flag, moff + (long)x * 256, yy * 256, lds);
}

// ---------------------------------------------------------------------------
// Per-token head mixing: scores = Q[16,64]@K[16,64]^T/8, softmax, Z = P@V.
// One wave per token, 4 tokens per 256-thread block.
// ---------------------------------------------------------------------------
__global__ __launch_bounds__(256) void attn_mix(const short* __restrict__ Q,
                                                const short* __restrict__ K,
                                                const short* __restrict__ V,
                                                short* __restrict__ Z) {
    constexpr int RS = 72;
    __shared__ short sq[4][16 * RS];
    __shared__ short sk[4][16 * RS];
    __shared__ short sv[4][16 * RS];
    __shared__ float sp[4][256];

    const int  tid  = threadIdx.x;
    const int  lane = tid & 63;
    const int  w    = tid >> 6;
    const long tok  = (long)blockIdx.x * 4 + w;

    const short* qg = Q + tok * 1024;
    const short* kg = K + tok * 1024;
    const short* vg = V + tok * 1024;

    #pragma unroll
    for (int it = 0; it < 2; ++it) {
        const int c   = lane + 64 * it;
        const int row = c >> 3;
        const int cc  = (c & 7) * 8;
        *(bf16x8*)&sq[w][row * RS + cc] = *(const bf16x8*)(qg + c * 8);
        *(bf16x8*)&sk[w][row * RS + cc] = *(const bf16x8*)(kg + c * 8);
        *(bf16x8*)&sv[w][row * RS + cc] = *(const bf16x8*)(vg + c * 8);
    }
    __syncthreads();

    const int h  = lane >> 2;
    const int t0 = (lane & 3) * 4;
    float sc[4] = {0.f, 0.f, 0.f, 0.f};
    for (int d = 0; d < 64; ++d) {
        const float qv = bf2f(sq[w][h * RS + d]);
        #pragma unroll
        for (int j = 0; j < 4; ++j)
            sc[j] += qv * bf2f(sk[w][(t0 + j) * RS + d]);
    }
    #pragma unroll
    for (int j = 0; j < 4; ++j) sc[j] *= 0.125f;

    float mx = fmaxf(fmaxf(sc[0], sc[1]), fmaxf(sc[2], sc[3]));
    mx = fmaxf(mx, __shfl_xor(mx, 1));
    mx = fmaxf(mx, __shfl_xor(mx, 2));
    float ex[4], s = 0.f;
    #pragma unroll
    for (int j = 0; j < 4; ++j) { ex[j] = __expf(sc[j] - mx); s += ex[j]; }
    s += __shfl_xor(s, 1);
    s += __shfl_xor(s, 2);
    const float inv = 1.f / s;
    #pragma unroll
    for (int j = 0; j < 4; ++j) sp[w][h * 16 + t0 + j] = ex[j] * inv;
    __syncthreads();

    const int dbase = (lane & 3) * 16;
    float o[16] = {};
    for (int t = 0; t < 16; ++t) {
        const float p = sp[w][h * 16 + t];
        const bf16x8 v0 = *(const bf16x8*)&sv[w][t * RS + dbase];
        const bf16x8 v1 = *(const bf16x8*)&sv[w][t * RS + dbase + 8];
        #pragma unroll
        for (int e = 0; e < 8; ++e) {
            o[e]     += p * bf2f(v0[e]);
            o[e + 8] += p * bf2f(v1[e]);
        }
    }
    bf16x8 ov0, ov1;
    #pragma unroll
    for (int e = 0; e < 8; ++e) { ov0[e] = f2bf(o[e]); ov1[e] = f2bf(o[e + 8]); }
    *(bf16x8*)(Z + tok * 1024 + lane * 16)     = ov0;
    *(bf16x8*)(Z + tok * 1024 + lane * 16 + 8) = ov1;
}

// ---------------------------------------------------------------------------
extern "C" void kernel_launch(void* const* d_in, const int* in_sizes, int n_in,
                              void* d_out, int out_size, void* d_ws, size_t ws_size,
                              hipStream_t stream) {
    const void* X = d_in[0];                   // [32768,1024] fp32 (detected)

    const long TOT = 32768;
    constexpr long WELEM = 1024 * 1024;

    char* ws   = (char*)d_ws;
    int*  flag = (int*)ws;
    short* Wqb = (short*)(ws + 256);
    short* Wkb = Wqb + WELEM;
    short* Wvb = Wkb + WELEM;
    short* Wob = Wvb + WELEM;
    short* dyn = Wob + WELEM;

    const size_t fixed = 256 + 4 * WELEM * 2;
    long chunk = 256;
    const long tiers[4] = {32768, 8192, 2048, 512};
    for (int i = 0; i < 4; ++i)
        if (fixed + (size_t)6 * tiers[i] * 1024 * 2 <= ws_size) { chunk = tiers[i]; break; }

    short* Xb = dyn;                 // chunk*1024 bf16
    short* Qb = Xb + chunk * 1024;
    short* Kb = Qb + chunk * 1024;
    short* Vb = Kb + chunk * 1024;
    short* Zb = Vb + chunk * 1024;

    detect_dtype<<<1, 256, 0, stream>>>((const unsigned*)X, flag);
    convert_any<<<512, 256, 0, stream>>>(d_in[1], 0, Wqb, WELEM, flag);
    convert_any<<<512, 256, 0, stream>>>(d_in[2], 0, Wkb, WELEM, flag);
    convert_any<<<512, 256, 0, stream>>>(d_in[3], 0, Wvb, WELEM, flag);
    convert_any<<<512, 256, 0, stream>>>(d_in[4], 0, Wob, WELEM, flag);

    for (long t0 = 0; t0 < TOT; t0 += chunk) {
        convert_any<<<2048, 256, 0, stream>>>(X, t0 * 1024, Xb, chunk * 1024, flag);
        gemm_qkv256<<<dim3((chunk / 256) * 12), 512, 0, stream>>>(Xb, Wqb, Wkb, Wvb,
                                                                  Qb, Kb, Vb);
        attn_mix<<<dim3(chunk / 4), 256, 0, stream>>>(Qb, Kb, Vb, Zb);
        gemm_out256<<<dim3((chunk / 256) * 4), 512, 0, stream>>>(Zb - t0 * 1024, Wob,
                                                                 d_out, t0, flag);
    }
}

// Round 5
// 415.523 us; speedup vs baseline: 1.3009x; 1.0342x over previous
//
#include <hip/hip_runtime.h>
#include <hip/hip_bf16.h>

// LlamaAttention_49392123904401 — per-token head-mixing "attention".
// fp32 inputs (runtime-detected), bf16 MFMA compute, output in input dtype.
// Round 5: 4-phase-per-K-tile interleaved schedule (T3) + counted vmcnt(2)
// (T4) + setprio (T5) on top of the round-4 256^2 tile / XOR-swizzle (T2) /
// XCD panel grouping (T1). Schedule derivation in round notes: per phase
// {stage 1 row-half unit of tile t+1 (2 gload_lds), vmcnt, barrier, 8 ds_read,
// 16 MFMA, barrier}; units ordered A.h0,A.h1,B.h0,B.h1 so HBM-sourced A has
// 3-4 phases of latency cover and L2-resident B needs only 1-2.

typedef short bf16x8 __attribute__((ext_vector_type(8)));   // 8 bf16 = 4 VGPRs
typedef float f32x4  __attribute__((ext_vector_type(4)));

__device__ __forceinline__ float bf2f(short u) {
    union { unsigned int ui; float f; } cv;
    cv.ui = ((unsigned int)(unsigned short)u) << 16;
    return cv.f;
}
__device__ __forceinline__ short f2bf(float f) {
    __hip_bfloat16 h = __float2bfloat16(f);
    return *reinterpret_cast<short*>(&h);
}

// async global->LDS, 16B per lane. LDS dest = wave-uniform base + lane*16.
__device__ __forceinline__ void gload_lds16(const void* g, void* lds) {
    const unsigned __attribute__((address_space(1)))* gp =
        reinterpret_cast<const unsigned __attribute__((address_space(1)))*>((unsigned long long)g);
    unsigned __attribute__((address_space(3)))* lp =
        reinterpret_cast<unsigned __attribute__((address_space(3)))*>(
            (unsigned int)(unsigned long long)lds);
    __builtin_amdgcn_global_load_lds(gp, lp, 16, 0, 0);
}

// ---------------------------------------------------------------------------
// dtype sniffer (flag: 1 = fp32 inputs, 0 = bf16 inputs).
// ---------------------------------------------------------------------------
__global__ void detect_dtype(const unsigned* __restrict__ x, int* __restrict__ flag) {
    __shared__ int cnt;
    if (threadIdx.x == 0) cnt = 0;
    __syncthreads();
    int c = 0;
    for (int i = threadIdx.x; i < 4096; i += 256) {
        const unsigned u = x[(long)i * 4001 + 3];
        const unsigned b = (u >> 7) & 0xFF;
        c += (b >= 0x70 && b <= 0x87) ? 1 : 0;
    }
    atomicAdd(&cnt, c);
    __syncthreads();
    if (threadIdx.x == 0) *flag = (cnt > 2048) ? 0 : 1;   // HIGH => bf16
}

// convert n elements (n % 8 == 0) at element offset eoff to bf16.
__global__ void convert_any(const void* __restrict__ src, long eoff,
                            short* __restrict__ dst, long n,
                            const int* __restrict__ flag) {
    const int f = *flag;
    const long step = (long)gridDim.x * blockDim.x * 8;
    for (long i = ((long)blockIdx.x * blockDim.x + threadIdx.x) * 8; i < n; i += step) {
        if (f) {
            const float* s = (const float*)src + eoff + i;
            const f32x4 a = *(const f32x4*)s;
            const f32x4 b = *(const f32x4*)(s + 4);
            bf16x8 o;
            o[0] = f2bf(a[0]); o[1] = f2bf(a[1]); o[2] = f2bf(a[2]); o[3] = f2bf(a[3]);
            o[4] = f2bf(b[0]); o[5] = f2bf(b[1]); o[6] = f2bf(b[2]); o[7] = f2bf(b[3]);
            *(bf16x8*)(dst + i) = o;
        } else {
            *(bf16x8*)(dst + i) = *(const bf16x8*)((const short*)src + eoff + i);
        }
    }
}

// ---------------------------------------------------------------------------
// 256x256 tile GEMM core: C[m0..+255][n0..+255] = A[.][1024] @ W[.][1024]^T
// 512 threads = 8 waves (2 M x 4 N), per-wave 128x64 output (8x4 frags).
// BK=64, 16 K-tiles, double-buffered, 4-phase interleaved schedule.
// LDS k-chunk XOR swizzle: phys_kc = kc ^ (row&7) (16B chunks, 8/row);
// staging pre-applies the inverse swizzle on the GLOBAL source address.
// ---------------------------------------------------------------------------
__device__ __forceinline__ void gemm256_core(const short* __restrict__ A,
                                             const short* __restrict__ W,
                                             void* __restrict__ C,
                                             const int* flag_fp32,
                                             long m0, int n0, short* lds) {
    constexpr int K = 1024, N = 1024;
    const int tid  = threadIdx.x;
    const int lane = tid & 63;
    const int wid  = tid >> 6;
    const int wm = wid >> 2, wn = wid & 3;

    short* A0 = lds;              // 16384 shorts = 32KB each
    short* B0 = lds + 16384;
    short* A1 = lds + 32768;
    short* B1 = lds + 49152;

    // staging source: thread covers (row = i*64 + tid>>3, phys kc = tid&7);
    // logical kc = phys ^ (row&7)  [row&7 == (tid>>3)&7 since i*64 % 8 == 0]
    const int srl = tid >> 3;                    // 0..63
    const int kcs = (tid & 7) ^ (srl & 7);       // logical k-chunk for this lane
    int aoff[4], boff[4];
    #pragma unroll
    for (int i = 0; i < 4; ++i) {
        const int row = i * 64 + srl;
        aoff[i] = (int)((m0 + row) * K + kcs * 8);
        boff[i] = (n0 + row) * K + kcs * 8;
    }
    const int ldsw = wid * 512;                  // wave's lane0 slot (shorts)

    f32x4 acc[8][4] = {};

    // prologue: tile 0 fully staged (8 loads/thread outstanding)
    #pragma unroll
    for (int i = 0; i < 4; ++i) gload_lds16(A + aoff[i], A0 + i * 4096 + ldsw);
    #pragma unroll
    for (int i = 0; i < 4; ++i) gload_lds16(W + boff[i], B0 + i * 4096 + ldsw);

    for (int t = 0; t < 16; ++t) {
        const int cur = t & 1;
        const short* rA = cur ? A1 : A0;         // read buffers (tile t)
        const short* rB = cur ? B1 : B0;
        short* sA = cur ? A0 : A1;               // stage buffers (tile t+1)
        short* sB = cur ? B0 : B1;
        const int kadd = (t + 1) * 64;
        const bool more = (t < 15);

        #pragma unroll
        for (int q = 0; q < 4; ++q) {
            // ---- stage one row-half unit of tile t+1 (2 gload_lds) ----
            if (more) {
                if (q == 0) {
                    gload_lds16(A + aoff[0] + kadd, sA + 0 * 4096 + ldsw);
                    gload_lds16(A + aoff[1] + kadd, sA + 1 * 4096 + ldsw);
                } else if (q == 1) {
                    gload_lds16(A + aoff[2] + kadd, sA + 2 * 4096 + ldsw);
                    gload_lds16(A + aoff[3] + kadd, sA + 3 * 4096 + ldsw);
                } else if (q == 2) {
                    gload_lds16(W + boff[0] + kadd, sB + 0 * 4096 + ldsw);
                    gload_lds16(W + boff[1] + kadd, sB + 1 * 4096 + ldsw);
                } else {
                    gload_lds16(W + boff[2] + kadd, sB + 2 * 4096 + ldsw);
                    gload_lds16(W + boff[3] + kadd, sB + 3 * 4096 + ldsw);
                }
            }
            // ---- tile-boundary wait: tile t fully landed ----
            if (q == 0) {
                if (more) asm volatile("s_waitcnt vmcnt(2)" ::: "memory");
                else      asm volatile("s_waitcnt vmcnt(0)" ::: "memory");
            }
            __builtin_amdgcn_s_barrier();            // barrier1: data ready, all waves
            __builtin_amdgcn_sched_barrier(0);
            // ---- ds_read frags for this quadrant: mf-half = q>>1, ks = q&1 ----
            const int mfh = q >> 1, ks = q & 1;
            const int kx8 = ((ks * 4 + (lane >> 4)) ^ (lane & 7)) * 8;
            bf16x8 af[4], bfr[4];
            #pragma unroll
            for (int m = 0; m < 4; ++m)
                af[m] = *(const bf16x8*)(rA + (wm * 128 + (mfh * 4 + m) * 16 + (lane & 15)) * 64 + kx8);
            #pragma unroll
            for (int n = 0; n < 4; ++n)
                bfr[n] = *(const bf16x8*)(rB + (wn * 64 + n * 16 + (lane & 15)) * 64 + kx8);
            __builtin_amdgcn_s_setprio(1);
            #pragma unroll
            for (int m = 0; m < 4; ++m)
                #pragma unroll
                for (int n = 0; n < 4; ++n)
                    acc[mfh * 4 + m][n] = __builtin_amdgcn_mfma_f32_16x16x32_bf16(
                                              af[m], bfr[n], acc[mfh * 4 + m][n], 0, 0, 0);
            __builtin_amdgcn_s_setprio(0);
            __builtin_amdgcn_s_barrier();            // barrier2: reads done before next stage
        }
    }

    // epilogue: C/D layout col=lane&15, row=(lane>>4)*4+r
    const int f = flag_fp32 ? *flag_fp32 : 0;
    #pragma unroll
    for (int mf = 0; mf < 8; ++mf) {
        #pragma unroll
        for (int nf = 0; nf < 4; ++nf) {
            const int  col   = n0 + wn * 64 + nf * 16 + (lane & 15);
            const long rbase = m0 + wm * 128 + mf * 16 + (lane >> 4) * 4;
            if (f) {
                float* Cf = (float*)C;
                #pragma unroll
                for (int r = 0; r < 4; ++r)
                    Cf[(rbase + r) * N + col] = acc[mf][nf][r];
            } else {
                short* Cs = (short*)C;
                #pragma unroll
                for (int r = 0; r < 4; ++r)
                    Cs[(rbase + r) * N + col] = f2bf(acc[mf][nf][r]);
            }
        }
    }
}

// QKV: 1-D grid, nwg = (Mc/256)*12. XCD-bijective remap with (n-tile, matrix)
// innermost so the 12 blocks sharing an A-panel run on one XCD.
__global__ __launch_bounds__(512, 2) void gemm_qkv256(const short* __restrict__ A,
                                                      const short* __restrict__ W0,
                                                      const short* __restrict__ W1,
                                                      const short* __restrict__ W2,
                                                      short* __restrict__ C0,
                                                      short* __restrict__ C1,
                                                      short* __restrict__ C2) {
    __shared__ __align__(16) short lds[65536];            // 128 KiB
    const int nwg = gridDim.x;
    const int q8  = nwg >> 3;
    const int d   = blockIdx.x;
    const int lin = (d & 7) * q8 + (d >> 3);
    const int x   = lin / 12;
    const int r   = lin - x * 12;
    const int yy  = r / 3;           // 0..3  (n-tile)
    const int z   = r - yy * 3;      // 0..2  (Q/K/V)
    const short* W = (z == 0) ? W0 : (z == 1) ? W1 : W2;
    short*       C = (z == 0) ? C0 : (z == 1) ? C1 : C2;
    gemm256_core(A, W, C, nullptr, (long)x * 256, yy * 256, lds);
}

// Output GEMM: 1-D grid, nwg = (Mc/256)*4. A pre-rebased by caller (A - moff*K).
__global__ __launch_bounds__(512, 2) void gemm_out256(const short* __restrict__ A,
                                                      const short* __restrict__ W,
                                                      void* __restrict__ C,
                                                      long moff,
                                                      const int* __restrict__ flag) {
    __shared__ __align__(16) short lds[65536];
    const int nwg = gridDim.x;
    const int q8  = nwg >> 3;
    const int d   = blockIdx.x;
    const int lin = (d & 7) * q8 + (d >> 3);
    const int x   = lin >> 2;
    const int yy  = lin & 3;
    gemm256_core(A, W, C, flag, moff + (long)x * 256, yy * 256, lds);
}

// ---------------------------------------------------------------------------
// Per-token head mixing: scores = Q[16,64]@K[16,64]^T/8, softmax, Z = P@V.
// One wave per token, 4 tokens per 256-thread block.
// ---------------------------------------------------------------------------
__global__ __launch_bounds__(256) void attn_mix(const short* __restrict__ Q,
                                                const short* __restrict__ K,
                                                const short* __restrict__ V,
                                                short* __restrict__ Z) {
    constexpr int RS = 72;
    __shared__ short sq[4][16 * RS];
    __shared__ short sk[4][16 * RS];
    __shared__ short sv[4][16 * RS];
    __shared__ float sp[4][256];

    const int  tid  = threadIdx.x;
    const int  lane = tid & 63;
    const int  w    = tid >> 6;
    const long tok  = (long)blockIdx.x * 4 + w;

    const short* qg = Q + tok * 1024;
    const short* kg = K + tok * 1024;
    const short* vg = V + tok * 1024;

    #pragma unroll
    for (int it = 0; it < 2; ++it) {
        const int c   = lane + 64 * it;
        const int row = c >> 3;
        const int cc  = (c & 7) * 8;
        *(bf16x8*)&sq[w][row * RS + cc] = *(const bf16x8*)(qg + c * 8);
        *(bf16x8*)&sk[w][row * RS + cc] = *(const bf16x8*)(kg + c * 8);
        *(bf16x8*)&sv[w][row * RS + cc] = *(const bf16x8*)(vg + c * 8);
    }
    __syncthreads();

    const int h  = lane >> 2;
    const int t0 = (lane & 3) * 4;
    float sc[4] = {0.f, 0.f, 0.f, 0.f};
    for (int d = 0; d < 64; ++d) {
        const float qv = bf2f(sq[w][h * RS + d]);
        #pragma unroll
        for (int j = 0; j < 4; ++j)
            sc[j] += qv * bf2f(sk[w][(t0 + j) * RS + d]);
    }
    #pragma unroll
    for (int j = 0; j < 4; ++j) sc[j] *= 0.125f;

    float mx = fmaxf(fmaxf(sc[0], sc[1]), fmaxf(sc[2], sc[3]));
    mx = fmaxf(mx, __shfl_xor(mx, 1));
    mx = fmaxf(mx, __shfl_xor(mx, 2));
    float ex[4], s = 0.f;
    #pragma unroll
    for (int j = 0; j < 4; ++j) { ex[j] = __expf(sc[j] - mx); s += ex[j]; }
    s += __shfl_xor(s, 1);
    s += __shfl_xor(s, 2);
    const float inv = 1.f / s;
    #pragma unroll
    for (int j = 0; j < 4; ++j) sp[w][h * 16 + t0 + j] = ex[j] * inv;
    __syncthreads();

    const int dbase = (lane & 3) * 16;
    float o[16] = {};
    for (int t = 0; t < 16; ++t) {
        const float p = sp[w][h * 16 + t];
        const bf16x8 v0 = *(const bf16x8*)&sv[w][t * RS + dbase];
        const bf16x8 v1 = *(const bf16x8*)&sv[w][t * RS + dbase + 8];
        #pragma unroll
        for (int e = 0; e < 8; ++e) {
            o[e]     += p * bf2f(v0[e]);
            o[e + 8] += p * bf2f(v1[e]);
        }
    }
    bf16x8 ov0, ov1;
    #pragma unroll
    for (int e = 0; e < 8; ++e) { ov0[e] = f2bf(o[e]); ov1[e] = f2bf(o[e + 8]); }
    *(bf16x8*)(Z + tok * 1024 + lane * 16)     = ov0;
    *(bf16x8*)(Z + tok * 1024 + lane * 16 + 8) = ov1;
}

// ---------------------------------------------------------------------------
extern "C" void kernel_launch(void* const* d_in, const int* in_sizes, int n_in,
                              void* d_out, int out_size, void* d_ws, size_t ws_size,
                              hipStream_t stream) {
    const void* X = d_in[0];                   // [32768,1024] fp32 (detected)

    const long TOT = 32768;
    constexpr long WELEM = 1024 * 1024;

    char* ws   = (char*)d_ws;
    int*  flag = (int*)ws;
    short* Wqb = (short*)(ws + 256);
    short* Wkb = Wqb + WELEM;
    short* Wvb = Wkb + WELEM;
    short* Wob = Wvb + WELEM;
    short* dyn = Wob + WELEM;

    const size_t fixed = 256 + 4 * WELEM * 2;
    long chunk = 256;
    const long tiers[4] = {32768, 8192, 2048, 512};
    for (int i = 0; i < 4; ++i)
        if (fixed + (size_t)6 * tiers[i] * 1024 * 2 <= ws_size) { chunk = tiers[i]; break; }

    short* Xb = dyn;                 // chunk*1024 bf16
    short* Qb = Xb + chunk * 1024;
    short* Kb = Qb + chunk * 1024;
    short* Vb = Kb + chunk * 1024;
    short* Zb = Vb + chunk * 1024;

    detect_dtype<<<1, 256, 0, stream>>>((const unsigned*)X, flag);
    convert_any<<<512, 256, 0, stream>>>(d_in[1], 0, Wqb, WELEM, flag);
    convert_any<<<512, 256, 0, stream>>>(d_in[2], 0, Wkb, WELEM, flag);
    convert_any<<<512, 256, 0, stream>>>(d_in[3], 0, Wvb, WELEM, flag);
    convert_any<<<512, 256, 0, stream>>>(d_in[4], 0, Wob, WELEM, flag);

    for (long t0 = 0; t0 < TOT; t0 += chunk) {
        convert_any<<<2048, 256, 0, stream>>>(X, t0 * 1024, Xb, chunk * 1024, flag);
        gemm_qkv256<<<dim3((chunk / 256) * 12), 512, 0, stream>>>(Xb, Wqb, Wkb, Wvb,
                                                                  Qb, Kb, Vb);
        attn_mix<<<dim3(chunk / 4), 256, 0, stream>>>(Qb, Kb, Vb, Zb);
        gemm_out256<<<dim3((chunk / 256) * 4), 512, 0, stream>>>(Zb - t0 * 1024, Wob,
                                                                 d_out, t0, flag);
    }
}

// Round 6
// 415.456 us; speedup vs baseline: 1.3011x; 1.0002x over previous
//
#include <hip/hip_runtime.h>
#include <hip/hip_bf16.h>

// LlamaAttention_49392123904401 — per-token head-mixing "attention".
// fp32 inputs (runtime-detected), bf16 MFMA compute, output in input dtype.
// Round 6: 2-phase-per-K-tile schedule with minimal LDS reads (24 b128/tile,
// B-frags no longer double-read), pre-barrier ds_reads (latency under barrier
// skew), 3 barriers + 1 vmcnt(0) per K-tile (derivation in round notes).
// Keeps round-4/5 proven pieces: 256^2 tile, XOR k-chunk swizzle (0 bank
// conflicts), XCD A-panel grouping, setprio around MFMA cluster.

typedef short bf16x8 __attribute__((ext_vector_type(8)));   // 8 bf16 = 4 VGPRs
typedef float f32x4  __attribute__((ext_vector_type(4)));

__device__ __forceinline__ float bf2f(short u) {
    union { unsigned int ui; float f; } cv;
    cv.ui = ((unsigned int)(unsigned short)u) << 16;
    return cv.f;
}
__device__ __forceinline__ short f2bf(float f) {
    __hip_bfloat16 h = __float2bfloat16(f);
    return *reinterpret_cast<short*>(&h);
}

// async global->LDS, 16B per lane. LDS dest = wave-uniform base + lane*16.
__device__ __forceinline__ void gload_lds16(const void* g, void* lds) {
    const unsigned __attribute__((address_space(1)))* gp =
        reinterpret_cast<const unsigned __attribute__((address_space(1)))*>((unsigned long long)g);
    unsigned __attribute__((address_space(3)))* lp =
        reinterpret_cast<unsigned __attribute__((address_space(3)))*>(
            (unsigned int)(unsigned long long)lds);
    __builtin_amdgcn_global_load_lds(gp, lp, 16, 0, 0);
}

// ---------------------------------------------------------------------------
// dtype sniffer (flag: 1 = fp32 inputs, 0 = bf16 inputs).
// ---------------------------------------------------------------------------
__global__ void detect_dtype(const unsigned* __restrict__ x, int* __restrict__ flag) {
    __shared__ int cnt;
    if (threadIdx.x == 0) cnt = 0;
    __syncthreads();
    int c = 0;
    for (int i = threadIdx.x; i < 4096; i += 256) {
        const unsigned u = x[(long)i * 4001 + 3];
        const unsigned b = (u >> 7) & 0xFF;
        c += (b >= 0x70 && b <= 0x87) ? 1 : 0;
    }
    atomicAdd(&cnt, c);
    __syncthreads();
    if (threadIdx.x == 0) *flag = (cnt > 2048) ? 0 : 1;   // HIGH => bf16
}

// convert n elements (n % 8 == 0) at element offset eoff to bf16.
__global__ void convert_any(const void* __restrict__ src, long eoff,
                            short* __restrict__ dst, long n,
                            const int* __restrict__ flag) {
    const int f = *flag;
    const long step = (long)gridDim.x * blockDim.x * 8;
    for (long i = ((long)blockIdx.x * blockDim.x + threadIdx.x) * 8; i < n; i += step) {
        if (f) {
            const float* s = (const float*)src + eoff + i;
            const f32x4 a = *(const f32x4*)s;
            const f32x4 b = *(const f32x4*)(s + 4);
            bf16x8 o;
            o[0] = f2bf(a[0]); o[1] = f2bf(a[1]); o[2] = f2bf(a[2]); o[3] = f2bf(a[3]);
            o[4] = f2bf(b[0]); o[5] = f2bf(b[1]); o[6] = f2bf(b[2]); o[7] = f2bf(b[3]);
            *(bf16x8*)(dst + i) = o;
        } else {
            *(bf16x8*)(dst + i) = *(const bf16x8*)((const short*)src + eoff + i);
        }
    }
}

// ---------------------------------------------------------------------------
// 256x256 tile GEMM core: C[m0..+255][n0..+255] = A[.][1024] @ W[.][1024]^T
// 512 threads = 8 waves (2 M x 4 N), per-wave 128x64 output (8x4 frags).
// BK=64, 16 K-tiles, double-buffered, 2 phases/tile (ks-halves).
// Per phase: 12 ds_read_b128 (pre-barrier) + 32 MFMA; stage A(t+1)@ph0,
// B(t+1)@ph1; vmcnt(0)+barrier once per tile (post-MFMA, ~0 stall).
// LDS k-chunk XOR swizzle: phys_kc = kc ^ (row&7); staging pre-applies the
// inverse swizzle on the GLOBAL source address (rule #21 both-sides).
// ---------------------------------------------------------------------------
__device__ __forceinline__ void gemm256_core(const short* __restrict__ A,
                                             const short* __restrict__ W,
                                             void* __restrict__ C,
                                             const int* flag_fp32,
                                             long m0, int n0, short* lds) {
    constexpr int K = 1024, N = 1024;
    const int tid  = threadIdx.x;
    const int lane = tid & 63;
    const int wid  = tid >> 6;
    const int wm = wid >> 2, wn = wid & 3;

    short* A0 = lds;              // 16384 shorts = 32KB each
    short* B0 = lds + 16384;
    short* A1 = lds + 32768;
    short* B1 = lds + 49152;

    // staging source: thread covers (row = i*64 + tid>>3, phys kc = tid&7);
    // logical kc = phys ^ (row&7)  [row&7 == (tid>>3)&7 since i*64 % 8 == 0]
    const int srl = tid >> 3;                    // 0..63
    const int kcs = (tid & 7) ^ (srl & 7);       // logical k-chunk for this lane
    int aoff[4], boff[4];
    #pragma unroll
    for (int i = 0; i < 4; ++i) {
        const int row = i * 64 + srl;
        aoff[i] = (int)((m0 + row) * K + kcs * 8);
        boff[i] = (n0 + row) * K + kcs * 8;
    }
    const int ldsw = wid * 512;                  // wave's lane0 slot (shorts)

    f32x4 acc[8][4] = {};

    // prologue: tile 0 fully staged, drained, synced
    #pragma unroll
    for (int i = 0; i < 4; ++i) gload_lds16(A + aoff[i], A0 + i * 4096 + ldsw);
    #pragma unroll
    for (int i = 0; i < 4; ++i) gload_lds16(W + boff[i], B0 + i * 4096 + ldsw);
    asm volatile("s_waitcnt vmcnt(0)" ::: "memory");
    __builtin_amdgcn_s_barrier();

    for (int t = 0; t < 16; ++t) {
        const int cur = t & 1;
        const short* rA = cur ? A1 : A0;         // read buffers (tile t)
        const short* rB = cur ? B1 : B0;
        short* sA = cur ? A0 : A1;               // stage buffers (tile t+1)
        short* sB = cur ? B0 : B1;
        const int kadd = (t + 1) * 64;
        const bool more = (t < 15);

        #pragma unroll
        for (int ks = 0; ks < 2; ++ks) {
            // ---- ds_read current tile's ks-half BEFORE the barrier: latency
            // hides under barrier-arrival skew / other waves' MFMA.
            const int kx8 = ((ks * 4 + (lane >> 4)) ^ (lane & 7)) * 8;
            bf16x8 af[8], bfr[4];
            #pragma unroll
            for (int m = 0; m < 8; ++m)
                af[m] = *(const bf16x8*)(rA + (wm * 128 + m * 16 + (lane & 15)) * 64 + kx8);
            #pragma unroll
            for (int n = 0; n < 4; ++n)
                bfr[n] = *(const bf16x8*)(rB + (wn * 64 + n * 16 + (lane & 15)) * 64 + kx8);
            __builtin_amdgcn_sched_barrier(0);
            __builtin_amdgcn_s_barrier();              // bar_a
            __builtin_amdgcn_sched_barrier(0);
            // ---- stage tile t+1 into the opposite buffer: A @ ks0, B @ ks1.
            // Safe: previous tile's reads of this region completed before the
            // last barrier (their lgkmcnt(0) precedes it).
            if (more) {
                if (ks == 0) {
                    #pragma unroll
                    for (int i = 0; i < 4; ++i)
                        gload_lds16(A + aoff[i] + kadd, sA + i * 4096 + ldsw);
                } else {
                    #pragma unroll
                    for (int i = 0; i < 4; ++i)
                        gload_lds16(W + boff[i] + kadd, sB + i * 4096 + ldsw);
                }
            }
            asm volatile("s_waitcnt lgkmcnt(0)" ::: "memory");
            __builtin_amdgcn_sched_barrier(0);         // rule 18: no MFMA hoist
            __builtin_amdgcn_s_setprio(1);
            #pragma unroll
            for (int m = 0; m < 8; ++m)
                #pragma unroll
                for (int n = 0; n < 4; ++n)
                    acc[m][n] = __builtin_amdgcn_mfma_f32_16x16x32_bf16(
                                    af[m], bfr[n], acc[m][n], 0, 0, 0);
            __builtin_amdgcn_s_setprio(0);
            __builtin_amdgcn_sched_barrier(0);
            if (ks == 1) {
                // tile boundary: all waves' t+1 stages landed before next reads.
                asm volatile("s_waitcnt vmcnt(0)" ::: "memory");
                __builtin_amdgcn_s_barrier();          // bar_b
            }
        }
    }

    // epilogue: C/D layout col=lane&15, row=(lane>>4)*4+r
    const int f = flag_fp32 ? *flag_fp32 : 0;
    #pragma unroll
    for (int mf = 0; mf < 8; ++mf) {
        #pragma unroll
        for (int nf = 0; nf < 4; ++nf) {
            const int  col   = n0 + wn * 64 + nf * 16 + (lane & 15);
            const long rbase = m0 + wm * 128 + mf * 16 + (lane >> 4) * 4;
            if (f) {
                float* Cf = (float*)C;
                #pragma unroll
                for (int r = 0; r < 4; ++r)
                    Cf[(rbase + r) * N + col] = acc[mf][nf][r];
            } else {
                short* Cs = (short*)C;
                #pragma unroll
                for (int r = 0; r < 4; ++r)
                    Cs[(rbase + r) * N + col] = f2bf(acc[mf][nf][r]);
            }
        }
    }
}

// QKV: 1-D grid, nwg = (Mc/256)*12. XCD-bijective remap with (n-tile, matrix)
// innermost so the 12 blocks sharing an A-panel run on one XCD.
__global__ __launch_bounds__(512, 2) void gemm_qkv256(const short* __restrict__ A,
                                                      const short* __restrict__ W0,
                                                      const short* __restrict__ W1,
                                                      const short* __restrict__ W2,
                                                      short* __restrict__ C0,
                                                      short* __restrict__ C1,
                                                      short* __restrict__ C2) {
    __shared__ __align__(16) short lds[65536];            // 128 KiB
    const int nwg = gridDim.x;
    const int q8  = nwg >> 3;
    const int d   = blockIdx.x;
    const int lin = (d & 7) * q8 + (d >> 3);
    const int x   = lin / 12;
    const int r   = lin - x * 12;
    const int yy  = r / 3;           // 0..3  (n-tile)
    const int z   = r - yy * 3;      // 0..2  (Q/K/V)
    const short* W = (z == 0) ? W0 : (z == 1) ? W1 : W2;
    short*       C = (z == 0) ? C0 : (z == 1) ? C1 : C2;
    gemm256_core(A, W, C, nullptr, (long)x * 256, yy * 256, lds);
}

// Output GEMM: 1-D grid, nwg = (Mc/256)*4. A pre-rebased by caller (A - moff*K).
__global__ __launch_bounds__(512, 2) void gemm_out256(const short* __restrict__ A,
                                                      const short* __restrict__ W,
                                                      void* __restrict__ C,
                                                      long moff,
                                                      const int* __restrict__ flag) {
    __shared__ __align__(16) short lds[65536];
    const int nwg = gridDim.x;
    const int q8  = nwg >> 3;
    const int d   = blockIdx.x;
    const int lin = (d & 7) * q8 + (d >> 3);
    const int x   = lin >> 2;
    const int yy  = lin & 3;
    gemm256_core(A, W, C, flag, moff + (long)x * 256, yy * 256, lds);
}

// ---------------------------------------------------------------------------
// Per-token head mixing: scores = Q[16,64]@K[16,64]^T/8, softmax, Z = P@V.
// One wave per token, 4 tokens per 256-thread block.
// ---------------------------------------------------------------------------
__global__ __launch_bounds__(256) void attn_mix(const short* __restrict__ Q,
                                                const short* __restrict__ K,
                                                const short* __restrict__ V,
                                                short* __restrict__ Z) {
    constexpr int RS = 72;
    __shared__ short sq[4][16 * RS];
    __shared__ short sk[4][16 * RS];
    __shared__ short sv[4][16 * RS];
    __shared__ float sp[4][256];

    const int  tid  = threadIdx.x;
    const int  lane = tid & 63;
    const int  w    = tid >> 6;
    const long tok  = (long)blockIdx.x * 4 + w;

    const short* qg = Q + tok * 1024;
    const short* kg = K + tok * 1024;
    const short* vg = V + tok * 1024;

    #pragma unroll
    for (int it = 0; it < 2; ++it) {
        const int c   = lane + 64 * it;
        const int row = c >> 3;
        const int cc  = (c & 7) * 8;
        *(bf16x8*)&sq[w][row * RS + cc] = *(const bf16x8*)(qg + c * 8);
        *(bf16x8*)&sk[w][row * RS + cc] = *(const bf16x8*)(kg + c * 8);
        *(bf16x8*)&sv[w][row * RS + cc] = *(const bf16x8*)(vg + c * 8);
    }
    __syncthreads();

    const int h  = lane >> 2;
    const int t0 = (lane & 3) * 4;
    float sc[4] = {0.f, 0.f, 0.f, 0.f};
    for (int d = 0; d < 64; ++d) {
        const float qv = bf2f(sq[w][h * RS + d]);
        #pragma unroll
        for (int j = 0; j < 4; ++j)
            sc[j] += qv * bf2f(sk[w][(t0 + j) * RS + d]);
    }
    #pragma unroll
    for (int j = 0; j < 4; ++j) sc[j] *= 0.125f;

    float mx = fmaxf(fmaxf(sc[0], sc[1]), fmaxf(sc[2], sc[3]));
    mx = fmaxf(mx, __shfl_xor(mx, 1));
    mx = fmaxf(mx, __shfl_xor(mx, 2));
    float ex[4], s = 0.f;
    #pragma unroll
    for (int j = 0; j < 4; ++j) { ex[j] = __expf(sc[j] - mx); s += ex[j]; }
    s += __shfl_xor(s, 1);
    s += __shfl_xor(s, 2);
    const float inv = 1.f / s;
    #pragma unroll
    for (int j = 0; j < 4; ++j) sp[w][h * 16 + t0 + j] = ex[j] * inv;
    __syncthreads();

    const int dbase = (lane & 3) * 16;
    float o[16] = {};
    for (int t = 0; t < 16; ++t) {
        const float p = sp[w][h * 16 + t];
        const bf16x8 v0 = *(const bf16x8*)&sv[w][t * RS + dbase];
        const bf16x8 v1 = *(const bf16x8*)&sv[w][t * RS + dbase + 8];
        #pragma unroll
        for (int e = 0; e < 8; ++e) {
            o[e]     += p * bf2f(v0[e]);
            o[e + 8] += p * bf2f(v1[e]);
        }
    }
    bf16x8 ov0, ov1;
    #pragma unroll
    for (int e = 0; e < 8; ++e) { ov0[e] = f2bf(o[e]); ov1[e] = f2bf(o[e + 8]); }
    *(bf16x8*)(Z + tok * 1024 + lane * 16)     = ov0;
    *(bf16x8*)(Z + tok * 1024 + lane * 16 + 8) = ov1;
}

// ---------------------------------------------------------------------------
extern "C" void kernel_launch(void* const* d_in, const int* in_sizes, int n_in,
                              void* d_out, int out_size, void* d_ws, size_t ws_size,
                              hipStream_t stream) {
    const void* X = d_in[0];                   // [32768,1024] fp32 (detected)

    const long TOT = 32768;
    constexpr long WELEM = 1024 * 1024;

    char* ws   = (char*)d_ws;
    int*  flag = (int*)ws;
    short* Wqb = (short*)(ws + 256);
    short* Wkb = Wqb + WELEM;
    short* Wvb = Wkb + WELEM;
    short* Wob = Wvb + WELEM;
    short* dyn = Wob + WELEM;

    const size_t fixed = 256 + 4 * WELEM * 2;
    long chunk = 256;
    const long tiers[4] = {32768, 8192, 2048, 512};
    for (int i = 0; i < 4; ++i)
        if (fixed + (size_t)6 * tiers[i] * 1024 * 2 <= ws_size) { chunk = tiers[i]; break; }

    short* Xb = dyn;                 // chunk*1024 bf16
    short* Qb = Xb + chunk * 1024;
    short* Kb = Qb + chunk * 1024;
    short* Vb = Kb + chunk * 1024;
    short* Zb = Vb + chunk * 1024;

    detect_dtype<<<1, 256, 0, stream>>>((const unsigned*)X, flag);
    convert_any<<<512, 256, 0, stream>>>(d_in[1], 0, Wqb, WELEM, flag);
    convert_any<<<512, 256, 0, stream>>>(d_in[2], 0, Wkb, WELEM, flag);
    convert_any<<<512, 256, 0, stream>>>(d_in[3], 0, Wvb, WELEM, flag);
    convert_any<<<512, 256, 0, stream>>>(d_in[4], 0, Wob, WELEM, flag);

    for (long t0 = 0; t0 < TOT; t0 += chunk) {
        convert_any<<<2048, 256, 0, stream>>>(X, t0 * 1024, Xb, chunk * 1024, flag);
        gemm_qkv256<<<dim3((chunk / 256) * 12), 512, 0, stream>>>(Xb, Wqb, Wkb, Wvb,
                                                                  Qb, Kb, Vb);
        attn_mix<<<dim3(chunk / 4), 256, 0, stream>>>(Qb, Kb, Vb, Zb);
        gemm_out256<<<dim3((chunk / 256) * 4), 512, 0, stream>>>(Zb - t0 * 1024, Wob,
                                                                 d_out, t0, flag);
    }
}